// Round 3
// baseline (1239.593 us; speedup 1.0000x reference)
//
#include <hip/hip_runtime.h>
#include <hip/hip_bf16.h>

#define DEVI __device__ __forceinline__

typedef __attribute__((ext_vector_type(8))) short  short8;
typedef __attribute__((ext_vector_type(4))) float  floatx4;
typedef __attribute__((ext_vector_type(8))) __bf16 bf16x8;

DEVI float b2f(unsigned short u){ union{unsigned int i; float f;} x; x.i=((unsigned int)u)<<16; return x.f; }
DEVI unsigned short f2b(float f){
  union{float ff; unsigned int i;} x; x.ff=f;
  unsigned int r = x.i + 0x7fffu + ((x.i>>16)&1u);
  return (unsigned short)(r>>16);
}

DEVI void lds_dma16(const void* g, void* l){
  __builtin_amdgcn_global_load_lds((const __attribute__((address_space(1))) void*)g,
                                   (__attribute__((address_space(3))) void*)l, 16, 0, 0);
}

DEVI floatx4 mfma_bf16(short8 a, short8 b, floatx4 c){
  return __builtin_amdgcn_mfma_f32_16x16x32_bf16(
      __builtin_bit_cast(bf16x8, a), __builtin_bit_cast(bf16x8, b), c, 0, 0, 0);
}

// ---------------------------------------------------------------------------
// f32 -> bf16 (single) elementwise
// ---------------------------------------------------------------------------
__global__ void cvt_kernel(const float* __restrict__ src, unsigned short* __restrict__ dst, int n8)
{
  const int i = blockIdx.x * 256 + threadIdx.x;
  if (i >= n8) return;
  floatx4 a = ((const floatx4*)src)[2*(size_t)i];
  floatx4 b = ((const floatx4*)src)[2*(size_t)i + 1];
  short8 o;
  o[0]=(short)f2b(a[0]); o[1]=(short)f2b(a[1]); o[2]=(short)f2b(a[2]); o[3]=(short)f2b(a[3]);
  o[4]=(short)f2b(b[0]); o[5]=(short)f2b(b[1]); o[6]=(short)f2b(b[2]); o[7]=(short)f2b(b[3]);
  *(short8*)&dst[(size_t)i*8] = o;
}

// ---------------------------------------------------------------------------
// f32 -> (hi, lo) bf16 split: hi = rne(x), lo = rne(x - hi). |x - hi - lo| ~ 2^-18|x|
// ---------------------------------------------------------------------------
__global__ void cvt_split(const float* __restrict__ src, unsigned short* __restrict__ dh,
                          unsigned short* __restrict__ dl, int n8)
{
  const int i = blockIdx.x * 256 + threadIdx.x;
  if (i >= n8) return;
  floatx4 a = ((const floatx4*)src)[2*(size_t)i];
  floatx4 b = ((const floatx4*)src)[2*(size_t)i + 1];
  short8 h, l;
  #pragma unroll
  for (int j = 0; j < 8; j++){
    float x = (j < 4) ? a[j] : b[j-4];
    unsigned short hb = f2b(x);
    h[j] = (short)hb;
    l[j] = (short)f2b(x - b2f(hb));
  }
  *(short8*)&dh[(size_t)i*8] = h;
  *(short8*)&dl[(size_t)i*8] = l;
}

// ---------------------------------------------------------------------------
// C(bf16) = A(f32) @ Bw(bf16)^T.  A staged with in-register f32->bf16 cvt,
// B via lds DMA. 128x128 tile, BK=32, 2x2 waves of 64x64.
// ---------------------------------------------------------------------------
__global__ __launch_bounds__(256, 2)
void gemm_af32(const float* __restrict__ A, const unsigned short* __restrict__ Bw,
               unsigned short* __restrict__ C, int M, int N, int K)
{
  __shared__ __align__(16) short As[128*32];
  __shared__ __align__(16) short Bs[128*32];
  const int t    = threadIdx.x;
  const int lane = t & 63;
  const int w    = t >> 6, wm = w >> 1, wn = w & 1;
  const int l15  = lane & 15, kg = lane >> 4;
  const long bm  = (long)blockIdx.y * 128, bn = (long)blockIdx.x * 128;

  const int r0 = t >> 2, c0 = (t & 3) * 8;           // B staging
  const unsigned short* pb0 = Bw + (bn + r0)      * K + c0;
  const unsigned short* pb1 = Bw + (bn + r0 + 64) * K + c0;
  short* lb0 = &Bs[t*8]; short* lb1 = &Bs[t*8 + 2048];

  const int ra = t >> 1, ca = (t & 1) * 16;          // A staging: 16 f32/thread
  const float* pa = A + (bm + ra) * (size_t)K + ca;
  short* la = &As[ra*32 + ca];

  floatx4 acc[4][4] = {};

  for (int k0 = 0; k0 < K; k0 += 32){
    __syncthreads();
    lds_dma16(pb0 + k0, lb0);
    lds_dma16(pb1 + k0, lb1);
    floatx4 a0 = *(const floatx4*)(pa + k0);
    floatx4 a1 = *(const floatx4*)(pa + k0 + 4);
    floatx4 a2 = *(const floatx4*)(pa + k0 + 8);
    floatx4 a3 = *(const floatx4*)(pa + k0 + 12);
    short8 s0, s1;
    s0[0]=(short)f2b(a0[0]); s0[1]=(short)f2b(a0[1]); s0[2]=(short)f2b(a0[2]); s0[3]=(short)f2b(a0[3]);
    s0[4]=(short)f2b(a1[0]); s0[5]=(short)f2b(a1[1]); s0[6]=(short)f2b(a1[2]); s0[7]=(short)f2b(a1[3]);
    s1[0]=(short)f2b(a2[0]); s1[1]=(short)f2b(a2[1]); s1[2]=(short)f2b(a2[2]); s1[3]=(short)f2b(a2[3]);
    s1[4]=(short)f2b(a3[0]); s1[5]=(short)f2b(a3[1]); s1[6]=(short)f2b(a3[2]); s1[7]=(short)f2b(a3[3]);
    *(short8*)la       = s0;
    *(short8*)(la + 8) = s1;
    __syncthreads();
    short8 af[4], bv[4];
    #pragma unroll
    for (int i = 0; i < 4; i++){
      af[i] = *(const short8*)&As[(wm*64 + i*16 + l15)*32 + kg*8];
      bv[i] = *(const short8*)&Bs[(wn*64 + i*16 + l15)*32 + kg*8];
    }
    #pragma unroll
    for (int i = 0; i < 4; i++)
      #pragma unroll
      for (int j = 0; j < 4; j++)
        acc[i][j] = mfma_bf16(af[i], bv[j], acc[i][j]);
  }

  #pragma unroll
  for (int i = 0; i < 4; i++){
    const long mb = bm + wm*64 + i*16 + kg*4;
    #pragma unroll
    for (int j = 0; j < 4; j++){
      const long n = bn + wn*64 + j*16 + l15;
      #pragma unroll
      for (int r = 0; r < 4; r++)
        C[(size_t)(mb + r) * N + n] = f2b(acc[i][j][r]);
    }
  }
}

// ---------------------------------------------------------------------------
// C(f32) = A(f32) @ B^T with split-bf16: A -> (ah, al) in-register; B pre-split
// (Bh, Bl). acc = ah*bh + ah*bl + al*bh  (lo*lo dropped, ~2^-18 rel error).
// QG=1: A-row gather r -> (r>>6)*4096 + (r&63).
// ---------------------------------------------------------------------------
template<int QG>
__global__ __launch_bounds__(256, 2)
void gemm_split(const float* __restrict__ A, const unsigned short* __restrict__ Bh,
                const unsigned short* __restrict__ Bl, float* __restrict__ C,
                int M, int N, int K)
{
  __shared__ __align__(16) short Ash[128*32];
  __shared__ __align__(16) short Asl[128*32];
  __shared__ __align__(16) short Bsh[128*32];
  __shared__ __align__(16) short Bsl[128*32];
  const int t    = threadIdx.x;
  const int lane = t & 63;
  const int w    = t >> 6, wm = w >> 1, wn = w & 1;
  const int l15  = lane & 15, kg = lane >> 4;
  const long bm  = (long)blockIdx.y * 128, bn = (long)blockIdx.x * 128;

  const int r0 = t >> 2, c0 = (t & 3) * 8;
  const unsigned short* pbh0 = Bh + (bn + r0)      * K + c0;
  const unsigned short* pbh1 = Bh + (bn + r0 + 64) * K + c0;
  const unsigned short* pbl0 = Bl + (bn + r0)      * K + c0;
  const unsigned short* pbl1 = Bl + (bn + r0 + 64) * K + c0;
  short* lbh0 = &Bsh[t*8]; short* lbh1 = &Bsh[t*8 + 2048];
  short* lbl0 = &Bsl[t*8]; short* lbl1 = &Bsl[t*8 + 2048];

  const int ra = t >> 1, ca = (t & 1) * 16;
  long arow = bm + ra;
  if (QG) arow = (arow >> 6) * 4096 + (arow & 63);
  const float* pa = A + arow * (size_t)K + ca;
  short* lah = &Ash[ra*32 + ca];
  short* lal = &Asl[ra*32 + ca];

  floatx4 acc[4][4] = {};

  for (int k0 = 0; k0 < K; k0 += 32){
    __syncthreads();
    lds_dma16(pbh0 + k0, lbh0);
    lds_dma16(pbh1 + k0, lbh1);
    lds_dma16(pbl0 + k0, lbl0);
    lds_dma16(pbl1 + k0, lbl1);
    float av[16];
    *(floatx4*)&av[0]  = *(const floatx4*)(pa + k0);
    *(floatx4*)&av[4]  = *(const floatx4*)(pa + k0 + 4);
    *(floatx4*)&av[8]  = *(const floatx4*)(pa + k0 + 8);
    *(floatx4*)&av[12] = *(const floatx4*)(pa + k0 + 12);
    short8 h0, h1, l0, l1;
    #pragma unroll
    for (int j = 0; j < 8; j++){
      unsigned short hb = f2b(av[j]);
      h0[j] = (short)hb; l0[j] = (short)f2b(av[j] - b2f(hb));
      unsigned short hb2 = f2b(av[8+j]);
      h1[j] = (short)hb2; l1[j] = (short)f2b(av[8+j] - b2f(hb2));
    }
    *(short8*)lah = h0; *(short8*)(lah + 8) = h1;
    *(short8*)lal = l0; *(short8*)(lal + 8) = l1;
    __syncthreads();
    short8 afh[4], afl[4], bvh[4], bvl[4];
    #pragma unroll
    for (int i = 0; i < 4; i++){
      afh[i] = *(const short8*)&Ash[(wm*64 + i*16 + l15)*32 + kg*8];
      afl[i] = *(const short8*)&Asl[(wm*64 + i*16 + l15)*32 + kg*8];
      bvh[i] = *(const short8*)&Bsh[(wn*64 + i*16 + l15)*32 + kg*8];
      bvl[i] = *(const short8*)&Bsl[(wn*64 + i*16 + l15)*32 + kg*8];
    }
    #pragma unroll
    for (int i = 0; i < 4; i++)
      #pragma unroll
      for (int j = 0; j < 4; j++){
        acc[i][j] = mfma_bf16(afh[i], bvh[j], acc[i][j]);
        acc[i][j] = mfma_bf16(afh[i], bvl[j], acc[i][j]);
        acc[i][j] = mfma_bf16(afl[i], bvh[j], acc[i][j]);
      }
  }

  #pragma unroll
  for (int i = 0; i < 4; i++){
    const long mb = bm + wm*64 + i*16 + kg*4;
    #pragma unroll
    for (int j = 0; j < 4; j++){
      const long n = bn + wn*64 + j*16 + l15;
      #pragma unroll
      for (int r = 0; r < 4; r++)
        C[(size_t)(mb + r) * N + n] = acc[i][j][r];
    }
  }
}

// ---------------------------------------------------------------------------
// In-place xpos on f32, position = row & smask.
// ---------------------------------------------------------------------------
__global__ void xpos_f32(float* __restrict__ X, int smask)
{
  const size_t idx = ((size_t)blockIdx.x * 256 + threadIdx.x) * 8;
  const int c = (int)(idx & 1023);
  const int r = (int)(idx >> 10);
  const int s = r & smask;
  const float fs = (float)s;
  floatx4 v0 = ((const floatx4*)X)[idx/4];
  floatx4 v1 = ((const floatx4*)X)[idx/4 + 1];
  float xi[8] = {v0[0],v0[1],v0[2],v0[3],v1[0],v1[1],v1[2],v1[3]};
  float xo[8];
  #pragma unroll
  for (int j = 0; j < 4; j++){
    const int i = (c >> 1) + j;
    float sv    = (2.0f*i + 409.6f) * (1.0f/1433.6f);
    float scale = __expf(__logf(sv) * fs * (1.0f/512.0f));
    float invf  = __expf(-(float)i * (9.2103403720f/512.0f));  // 10000^(-i/512)
    float ang   = fs * invf;
    float sn, cs;
    __sincosf(ang, &sn, &cs);
    sn *= scale; cs *= scale;
    float x1 = xi[2*j], x2 = xi[2*j+1];
    xo[2*j]   = x1*cs - x2*sn;
    xo[2*j+1] = x2*cs + x1*sn;
  }
  floatx4 o0 = {xo[0],xo[1],xo[2],xo[3]}, o1 = {xo[4],xo[5],xo[6],xo[7]};
  ((floatx4*)X)[idx/4]     = o0;
  ((floatx4*)X)[idx/4 + 1] = o1;
}

// ---------------------------------------------------------------------------
// Split-precision projection: P[b*2][e][d'] += sum_s wxw[e,s]*X[b][s,d'],
// X f32 (split in-register), wxw pre-split (h,l). 3-term MFMA.
// ---------------------------------------------------------------------------
__global__ __launch_bounds__(256, 2)
void proj_split(const float* __restrict__ X0, const unsigned short* __restrict__ wxh,
                const unsigned short* __restrict__ wxl, float* __restrict__ P)
{
  __shared__ __align__(16) short Wsh[64*32];
  __shared__ __align__(16) short Wsl[64*32];
  __shared__ __align__(16) short Xth[64*40];
  __shared__ __align__(16) short Xtl[64*40];
  const int t = threadIdx.x, w = t >> 6, lane = t & 63;
  const int l15 = lane & 15, kg = lane >> 4;
  const int d0 = blockIdx.x * 64;
  const int b  = blockIdx.y;
  const float* X = X0 + (size_t)b * 4096 * 1024;
  const int s0 = blockIdx.z * 512;
  const int ssr = t >> 3, ddr = (t & 7) * 8;
  floatx4 acc[4] = {};

  for (int kk = 0; kk < 512; kk += 32){
    const int s = s0 + kk;
    floatx4 x0 = *(const floatx4*)&X[(size_t)(s + ssr) * 1024 + d0 + ddr];
    floatx4 x1 = *(const floatx4*)&X[(size_t)(s + ssr) * 1024 + d0 + ddr + 4];
    __syncthreads();
    lds_dma16(&wxh[(size_t)(t >> 2) * 4096 + s + (t & 3) * 8], &Wsh[t*8]);
    lds_dma16(&wxl[(size_t)(t >> 2) * 4096 + s + (t & 3) * 8], &Wsl[t*8]);
    float xv[8] = {x0[0],x0[1],x0[2],x0[3],x1[0],x1[1],x1[2],x1[3]};
    #pragma unroll
    for (int j = 0; j < 8; j++){
      unsigned short hb = f2b(xv[j]);
      Xth[(ddr + j) * 40 + ssr] = (short)hb;
      Xtl[(ddr + j) * 40 + ssr] = (short)f2b(xv[j] - b2f(hb));
    }
    __syncthreads();
    short8 afh = *(const short8*)&Wsh[(w*16 + l15)*32 + kg*8];
    short8 afl = *(const short8*)&Wsl[(w*16 + l15)*32 + kg*8];
    #pragma unroll
    for (int j = 0; j < 4; j++){
      short8 bvh = *(const short8*)&Xth[(j*16 + l15)*40 + kg*8];
      short8 bvl = *(const short8*)&Xtl[(j*16 + l15)*40 + kg*8];
      acc[j] = mfma_bf16(afh, bvh, acc[j]);
      acc[j] = mfma_bf16(afh, bvl, acc[j]);
      acc[j] = mfma_bf16(afl, bvh, acc[j]);
    }
  }
  float* Pb = P + (size_t)(b*2) * 65536;
  #pragma unroll
  for (int j = 0; j < 4; j++)
    #pragma unroll
    for (int r = 0; r < 4; r++)
      atomicAdd(&Pb[(w*16 + kg*4 + r) * 1024 + d0 + j*16 + l15], acc[j][r]);
}

// ---------------------------------------------------------------------------
// bf16 projection for V: P[b*2+1][e][d'] += sum_s wxw_h[e,s]*X[b][s,d']
// ---------------------------------------------------------------------------
__global__ __launch_bounds__(256, 2)
void proj_bf16(const unsigned short* __restrict__ X0, const unsigned short* __restrict__ wxw_bf,
               float* __restrict__ P)
{
  __shared__ __align__(16) short Ws[64*32];
  __shared__ __align__(16) short Xt[64*40];
  const int t = threadIdx.x, w = t >> 6, lane = t & 63;
  const int l15 = lane & 15, kg = lane >> 4;
  const int d0 = blockIdx.x * 64;
  const int b  = blockIdx.y;
  const unsigned short* X = X0 + (size_t)b * 4096 * 1024;
  const int s0 = blockIdx.z * 512;
  const int ssr = t >> 3, ddr = (t & 7) * 8;
  floatx4 acc[4] = {};

  for (int kk = 0; kk < 512; kk += 32){
    const int s = s0 + kk;
    short8 xv = *(const short8*)&X[(size_t)(s + ssr) * 1024 + d0 + ddr];
    __syncthreads();
    lds_dma16(&wxw_bf[(size_t)(t >> 2) * 4096 + s + (t & 3) * 8], &Ws[t*8]);
    #pragma unroll
    for (int j = 0; j < 8; j++) Xt[(ddr + j) * 40 + ssr] = xv[j];
    __syncthreads();
    short8 af = *(const short8*)&Ws[(w*16 + l15)*32 + kg*8];
    #pragma unroll
    for (int j = 0; j < 4; j++){
      short8 bv = *(const short8*)&Xt[(j*16 + l15)*40 + kg*8];
      acc[j] = mfma_bf16(af, bv, acc[j]);
    }
  }
  float* Pb = P + (size_t)(b*2 + 1) * 65536;
  #pragma unroll
  for (int j = 0; j < 4; j++)
    #pragma unroll
    for (int r = 0; r < 4; r++)
      atomicAdd(&Pb[(w*16 + kg*4 + r) * 1024 + d0 + j*16 + l15], acc[j][r]);
}

// ---------------------------------------------------------------------------
// Per (b,h) attention + group norm. Masked score entries are literal ZEROS.
// ---------------------------------------------------------------------------
__global__ void attn_kernel(const float* __restrict__ P, const float* __restrict__ Qx,
                            const float* __restrict__ wxb,
                            const float* __restrict__ gnw, const float* __restrict__ gnb,
                            float* __restrict__ zs, float* __restrict__ zc)
{
  __shared__ __align__(16) float kps[64*64];   // [e][d]
  __shared__ __align__(16) float vps[64*64];   // [e][f]
  __shared__ float ym[64];
  const int lane = threadIdx.x;
  const int b = blockIdx.x >> 4, h = blockIdx.x & 15;
  const float* Pk = P + (size_t)(2*b) * 65536 + h*64;
  const float* Pv = Pk + 65536;
  for (int e = 0; e < 64; e++){
    float wb = wxb[e];
    kps[e*64 + lane] = Pk[(size_t)e*1024 + lane] + wb;
    vps[e*64 + lane] = Pv[(size_t)e*1024 + lane] + wb;
  }
  __syncthreads();

  const float lg = -3.4657359028f - 0.1848392483f * (float)h;
  const float gamma = 1.0f - __expf(lg);
  const int s = lane;

  float qf[64];
  const floatx4* q4 = (const floatx4*)(Qx + (size_t)(b*64 + s)*1024 + h*64);
  #pragma unroll
  for (int i = 0; i < 16; i++){
    floatx4 qq = q4[i];
    qf[4*i] = qq.x; qf[4*i+1] = qq.y; qf[4*i+2] = qq.z; qf[4*i+3] = qq.w;
  }

  float sc[64];
  #pragma unroll
  for (int e = 0; e < 64; e++){
    const floatx4* kp4 = (const floatx4*)&kps[e*64];
    float dot = 0.f;
    #pragma unroll
    for (int d = 0; d < 16; d++){
      floatx4 kv = kp4[d];
      dot += qf[4*d]*kv.x + qf[4*d+1]*kv.y + qf[4*d+2]*kv.z + qf[4*d+3]*kv.w;
    }
    sc[e] = dot;
  }
  float dec = 1.0f;
  #pragma unroll
  for (int e = 0; e < 64; e++){
    bool on = (e >= s);
    sc[e] = on ? sc[e]*dec : 0.0f;
    if (on) dec *= gamma;
  }
  float mx = -1e30f;
  #pragma unroll
  for (int e = 0; e < 64; e++) mx = fmaxf(mx, sc[e]);
  float Z = 0.f;
  #pragma unroll
  for (int e = 0; e < 64; e++){ sc[e] = __expf(sc[e] - mx); Z += sc[e]; }
  const float rz = 1.0f / Z;

  #pragma unroll
  for (int g = 0; g < 16; g++){
    floatx4 y = {0.f,0.f,0.f,0.f};
    #pragma unroll
    for (int e = 0; e < 64; e++){
      floatx4 vv = *(const floatx4*)&vps[e*64 + g*4];
      y += sc[e] * vv;
    }
    y *= rz;
    float mu = (y.x + y.y + y.z + y.w) * 0.25f;
    float a0 = y.x-mu, a1 = y.y-mu, a2 = y.z-mu, a3 = y.w-mu;
    float inv = rsqrtf((a0*a0 + a1*a1 + a2*a2 + a3*a3)*0.25f + 1e-5f);
    floatx4 o;
    o.x = a0*inv*gnw[g*4+0] + gnb[g*4+0];
    o.y = a1*inv*gnw[g*4+1] + gnb[g*4+1];
    o.z = a2*inv*gnw[g*4+2] + gnb[g*4+2];
    o.w = a3*inv*gnw[g*4+3] + gnb[g*4+3];
    *(floatx4*)&zs[(size_t)(b*64 + s)*1024 + h*64 + g*4] = o;
  }

  float am = 0.f;
  for (int e = 0; e < 64; e++) am += vps[e*64 + lane];
  ym[lane] = am * (1.0f/64.0f);
  __syncthreads();
  if (lane < 16){
    float a0 = ym[lane*4], a1 = ym[lane*4+1], a2 = ym[lane*4+2], a3 = ym[lane*4+3];
    float mu = (a0+a1+a2+a3)*0.25f;
    a0 -= mu; a1 -= mu; a2 -= mu; a3 -= mu;
    float inv = rsqrtf((a0*a0+a1*a1+a2*a2+a3*a3)*0.25f + 1e-5f);
    zc[(size_t)b*1024 + h*64 + lane*4+0] = a0*inv*gnw[lane*4+0] + gnb[lane*4+0];
    zc[(size_t)b*1024 + h*64 + lane*4+1] = a1*inv*gnw[lane*4+1] + gnb[lane*4+1];
    zc[(size_t)b*1024 + h*64 + lane*4+2] = a2*inv*gnw[lane*4+2] + gnb[lane*4+2];
    zc[(size_t)b*1024 + h*64 + lane*4+3] = a3*inv*gnw[lane*4+3] + gnb[lane*4+3];
  }
}

// ---------------------------------------------------------------------------
// In-place: G <- silu(G * z)
// ---------------------------------------------------------------------------
__global__ void gate_prep(unsigned short* __restrict__ G, const float* __restrict__ zs,
                          const float* __restrict__ zc)
{
  const size_t idx = ((size_t)blockIdx.x * 256 + threadIdx.x) * 8;
  const int r = (int)(idx >> 10), c = (int)(idx & 1023);
  const int b = r >> 12, s = r & 4095;
  const float* z = (s < 64) ? &zs[(size_t)(b*64 + s)*1024 + c] : &zc[(size_t)b*1024 + c];
  short8 gv = *(const short8*)&G[idx];
  short8 ov;
  #pragma unroll
  for (int j = 0; j < 8; j++){
    float g = b2f((unsigned short)gv[j]) * z[j];
    float sig = 1.0f / (1.0f + __expf(-g));
    ov[j] = (short)f2b(g * sig);
  }
  *(short8*)&G[idx] = ov;
}

// ---------------------------------------------------------------------------
// C(f32) = A(bf16) @ B(bf16)^T — final GEMM (both operands DMA-staged).
// ---------------------------------------------------------------------------
__global__ __launch_bounds__(256, 2)
void gemm_bt(const unsigned short* __restrict__ A, const unsigned short* __restrict__ Bw,
             float* __restrict__ C, int M, int N, int K)
{
  __shared__ __align__(16) short As[128*32];
  __shared__ __align__(16) short Bs[128*32];
  const int t    = threadIdx.x;
  const int lane = t & 63;
  const int w    = t >> 6, wm = w >> 1, wn = w & 1;
  const int l15  = lane & 15, kg = lane >> 4;
  const long bm  = (long)blockIdx.y * 128, bn = (long)blockIdx.x * 128;

  const int r0 = t >> 2, c0 = (t & 3) * 8;
  const unsigned short* pa0 = A  + (bm + r0)      * K + c0;
  const unsigned short* pa1 = A  + (bm + r0 + 64) * K + c0;
  const unsigned short* pb0 = Bw + (bn + r0)      * K + c0;
  const unsigned short* pb1 = Bw + (bn + r0 + 64) * K + c0;
  short* la0 = &As[t*8]; short* la1 = &As[t*8 + 2048];
  short* lb0 = &Bs[t*8]; short* lb1 = &Bs[t*8 + 2048];

  floatx4 acc[4][4] = {};

  for (int k0 = 0; k0 < K; k0 += 32){
    __syncthreads();
    lds_dma16(pa0 + k0, la0);
    lds_dma16(pa1 + k0, la1);
    lds_dma16(pb0 + k0, lb0);
    lds_dma16(pb1 + k0, lb1);
    __syncthreads();
    short8 af[4], bv[4];
    #pragma unroll
    for (int i = 0; i < 4; i++){
      af[i] = *(const short8*)&As[(wm*64 + i*16 + l15)*32 + kg*8];
      bv[i] = *(const short8*)&Bs[(wn*64 + i*16 + l15)*32 + kg*8];
    }
    #pragma unroll
    for (int i = 0; i < 4; i++)
      #pragma unroll
      for (int j = 0; j < 4; j++)
        acc[i][j] = mfma_bf16(af[i], bv[j], acc[i][j]);
  }

  #pragma unroll
  for (int i = 0; i < 4; i++){
    const long mb = bm + wm*64 + i*16 + kg*4;
    #pragma unroll
    for (int j = 0; j < 4; j++){
      const long n = bn + wn*64 + j*16 + l15;
      #pragma unroll
      for (int r = 0; r < 4; r++)
        C[(size_t)(mb + r) * N + n] = acc[i][j][r];
    }
  }
}

// ---------------------------------------------------------------------------
extern "C" void kernel_launch(void* const* d_in, const int* in_sizes, int n_in,
                              void* d_out, int out_size, void* d_ws, size_t ws_size,
                              hipStream_t stream)
{
  const float* q   = (const float*)d_in[0];
  const float* k   = (const float*)d_in[1];
  const float* v   = (const float*)d_in[2];
  const float* wq  = (const float*)d_in[3];
  const float* wk  = (const float*)d_in[4];
  const float* wv  = (const float*)d_in[5];
  const float* wo  = (const float*)d_in[6];
  const float* wg  = (const float*)d_in[7];
  const float* wxw = (const float*)d_in[8];
  const float* wxb = (const float*)d_in[9];
  const float* gnw = (const float*)d_in[10];
  const float* gnb = (const float*)d_in[11];

  // ws layout (47.2 MB). d_out (f32, 64 MB) doubles as Kx f32 scratch.
  char* ws = (char*)d_ws;
  unsigned short* A0   = (unsigned short*)(ws);             // 32 MB: Vx bf16 -> Agate bf16
  unsigned short* wh   = (unsigned short*)(ws + 33554432);  // 2 MB: wk_h -> wq_h
  unsigned short* wl   = (unsigned short*)(ws + 35651584);  // 2 MB: wk_l -> wq_l
  unsigned short* wAbf = (unsigned short*)(ws + 37748736);  // 2 MB: wv -> wo
  unsigned short* wgbf = (unsigned short*)(ws + 39845888);  // 2 MB
  unsigned short* wxh  = (unsigned short*)(ws + 41943040);  // 512 KB
  unsigned short* wxl  = (unsigned short*)(ws + 42467328);  // 512 KB
  float*          P    = (float*)(ws + 42991616);           // 2 MB
  float*          zs   = (float*)(ws + 45088768);           // 1 MB
  float*          zc   = (float*)(ws + 46137344);           // 16 KB
  float*          Qx   = (float*)(ws + 46153728);           // 1 MB
  float*          Kx   = (float*)d_out;                     // 64 MB f32 scratch

  const int M = 16384, N = 1024, K = 1024;
  dim3 blk(256);

  // weight prep (phase 1)
  cvt_split<<<512, blk, 0, stream>>>(wk, wh, wl, 131072);
  cvt_split<<<128, blk, 0, stream>>>(wxw, wxh, wxl, 32768);
  cvt_kernel<<<512, blk, 0, stream>>>(wv, wAbf, 131072);
  cvt_kernel<<<512, blk, 0, stream>>>(wg, wgbf, 131072);
  hipMemsetAsync(P, 0, 2097152, stream);

  // K path (split precision): k @ wk^T -> Kx f32 (in d_out), xpos, proj
  gemm_split<0><<<dim3(8,128), blk, 0, stream>>>(k, wh, wl, Kx, M, N, K);
  xpos_f32<<<8192, blk, 0, stream>>>(Kx, 4095);
  proj_split<<<dim3(16,4,8), blk, 0, stream>>>(Kx, wxh, wxl, P);

  // V path (bf16): v @ wv^T -> A0 bf16, proj
  gemm_af32<<<dim3(8,128), blk, 0, stream>>>(v, wAbf, A0, M, N, K);
  proj_bf16<<<dim3(16,4,8), blk, 0, stream>>>(A0, wxh, P);
  cvt_kernel<<<512, blk, 0, stream>>>(wo, wAbf, 131072);   // wv dead -> wo

  // Q path (split precision): gather 64 rows/batch, xpos, attention
  cvt_split<<<512, blk, 0, stream>>>(wq, wh, wl, 131072);  // wk dead -> wq
  gemm_split<1><<<dim3(8,2), blk, 0, stream>>>(q, wh, wl, Qx, 256, N, K);
  xpos_f32<<<128, blk, 0, stream>>>(Qx, 63);
  attn_kernel<<<64, 64, 0, stream>>>(P, Qx, wxb, gnw, gnb, zs, zc);

  // Gate path: G = q @ wg^T -> A0 (Vx dead), silu-gate, final GEMM -> d_out
  gemm_af32<<<dim3(8,128), blk, 0, stream>>>(q, wgbf, A0, M, N, K);
  gate_prep<<<8192, blk, 0, stream>>>(A0, zs, zc);
  gemm_bt<<<dim3(8,128), blk, 0, stream>>>(A0, wAbf, (float*)d_out, M, N, K);
}